// Round 17
// baseline (236.539 us; speedup 1.0000x reference)
//
#include <hip/hip_runtime.h>

typedef unsigned short u16;
typedef __attribute__((ext_vector_type(8))) __bf16 bf16x8;
typedef __attribute__((ext_vector_type(4))) float f32x4;

#define GLD_LDS(src, dst) \
  __builtin_amdgcn_global_load_lds((const __attribute__((address_space(1))) void*)(src), \
                                   (__attribute__((address_space(3))) void*)(dst), 16, 0, 0)

__device__ __forceinline__ u16 f2bf(float f) {
  union { float f; unsigned int u; } c; c.f = f;
  unsigned int u = c.u + 0x7FFFu + ((c.u >> 16) & 1u);
  return (u16)(u >> 16);
}

__device__ __forceinline__ unsigned int cvt_pk_bf16(float lo, float hi) {
  unsigned int r;
  asm("v_cvt_pk_bf16_f32 %0, %1, %2" : "=v"(r) : "v"(lo), "v"(hi));
  return r;
}

// sigma key-permutation within each 64-block (bit perm: keeps bits 0,1,5; 2->3->4->2)
// so attn's P^T B-fragment is exactly the lane-local cvt_pk-packed S registers.
__device__ __forceinline__ int vpos(int n) {
  return (n & ~63) | (n & 0x23) | ((n & 0x0C) << 1) | ((n & 0x10) >> 2);
}

// ---------------- Fused prep: LN + both weight transposes in ONE dispatch ----------------
__device__ __forceinline__ void ln_body(const float* __restrict__ x,
    const float* __restrict__ gamma, const float* __restrict__ beta,
    u16* __restrict__ xn, int row, int tid, float* red)
{
  const int lane = tid & 63, wave = tid >> 6;
  const float4 v = ((const float4*)(x + (size_t)row * 1024))[tid];
  float s = v.x + v.y + v.z + v.w;
  float q = v.x*v.x + v.y*v.y + v.z*v.z + v.w*v.w;
  #pragma unroll
  for (int m = 1; m < 64; m <<= 1) { s += __shfl_xor(s, m, 64); q += __shfl_xor(q, m, 64); }
  if (lane == 0) { red[wave] = s; red[4 + wave] = q; }
  __syncthreads();
  s = red[0] + red[1] + red[2] + red[3];
  q = red[4] + red[5] + red[6] + red[7];
  const float mu = s * (1.0f/1024.0f);
  const float var = q * (1.0f/1024.0f) - mu*mu;
  const float rs = rsqrtf(var + 1e-5f);
  const float4 gm = ((const float4*)gamma)[tid];
  const float4 bt = ((const float4*)beta)[tid];
  unsigned int w0 = (unsigned int)f2bf((v.x - mu)*rs*gm.x + bt.x)
                  | ((unsigned int)f2bf((v.y - mu)*rs*gm.y + bt.y) << 16);
  unsigned int w1 = (unsigned int)f2bf((v.z - mu)*rs*gm.z + bt.z)
                  | ((unsigned int)f2bf((v.w - mu)*rs*gm.w + bt.w) << 16);
  uint2 o; o.x = w0; o.y = w1;
  ((uint2*)(xn + (size_t)row * 1024))[tid] = o;
}

__device__ __forceinline__ void tcvt_body(const float* __restrict__ in, u16* __restrict__ out,
    int K, int N, int scaleLim, int bx, int by, int tid, float* t /*32x33*/)
{
  const int n0 = bx * 32, k0 = by * 32;
  const int lx = tid & 31, ly = tid >> 5;  // 32x8
  #pragma unroll
  for (int i = 0; i < 32; i += 8)
    t[(ly + i) * 33 + lx] = in[(size_t)(k0 + ly + i) * N + n0 + lx];
  __syncthreads();
  #pragma unroll
  for (int i = 0; i < 32; i += 8) {
    int n = n0 + ly + i;
    float v = t[lx * 33 + ly + i];
    if (n < scaleLim) v *= 0.18033688011116011f;   // 0.125 * log2(e)
    out[(size_t)n * K + k0 + lx] = f2bf(v);
  }
}

__global__ __launch_bounds__(256) void prep_kernel(
    const float* __restrict__ x, const float* __restrict__ gamma,
    const float* __restrict__ beta, u16* __restrict__ xn,
    const float* __restrict__ w_qkv, u16* __restrict__ wqkvT,
    const float* __restrict__ w_out, u16* __restrict__ woutT)
{
  __shared__ float smem[32 * 33];
  const int blk = blockIdx.x, tid = threadIdx.x;
  if (blk < 4096) {
    ln_body(x, gamma, beta, xn, blk, tid, smem);
  } else if (blk < 4096 + 3072) {
    const int j = blk - 4096;
    tcvt_body(w_qkv, wqkvT, 1024, 3072, 1024, j % 96, j / 96, tid, smem);
  } else {
    const int j = blk - 7168;
    tcvt_body(w_out, woutT, 1024, 1024, 0, j % 32, j / 32, tid, smem);
  }
}

// ---------------- GEMM: C[M][N] = A[M][K] * BT[N][K]^T, bf16 in, fp32 acc ----------------
// Single-buffer + XCD swizzle (r10/r13-verified), templated on BN and wave grid WMxWN.
// !FINAL (gemm1, N=3072): cols <2048 (Q,K) -> outB [4096][2048]; cols >=2048 (V) -> written
// TRANSPOSED + sigma-permuted directly into outV (vt) from the accumulator (r14-verified).
template<bool FINAL, int BN, int WM, int WN>
__global__ __launch_bounds__(WM*WN*64, 2) void gemm_bt(
    const u16* __restrict__ A, const u16* __restrict__ BT,
    u16* __restrict__ outB, u16* __restrict__ outV, float* __restrict__ outF,
    const float* __restrict__ bias, int M, int N, int K)
{
  constexpr int TW = WM * WN;          // waves per block
  constexpr int MF = 128 / (16 * WM);  // m-frags per wave
  constexpr int NF = BN / (16 * WN);   // n-frags per wave
  __shared__ __align__(16) u16 Alds[128 * 64];
  __shared__ __align__(16) u16 Blds[BN * 64];
  const int tid = threadIdx.x, wave = tid >> 6, lane = tid & 63;
  const int r15 = lane & 15, g = lane >> 4, l8 = lane >> 3, c8 = lane & 7;

  // XCD swizzle (bijective: nwg % 8 == 0)
  const int nwgx = gridDim.x;
  const int lin = blockIdx.x + blockIdx.y * nwgx;
  const int cpx = (nwgx * gridDim.y) >> 3;
  const int swz = (lin & 7) * cpx + (lin >> 3);
  const int row0 = (swz / nwgx) * 128, col0 = (swz % nwgx) * BN;

  const int wm = (wave / WN) * (128 / WM);
  const int wn = (wave % WN) * (BN / WN);
  const int srcCol = (c8 ^ l8) << 3;

  f32x4 acc[MF][NF] = {};

  for (int kt = 0; kt < K; kt += 64) {
    #pragma unroll
    for (int c = 0; c < 16 / TW; ++c) {
      const int r0 = wave * (128 / TW) + c * 8;
      GLD_LDS(A + (size_t)(row0 + r0 + l8) * K + kt + srcCol, Alds + r0 * 64);
    }
    #pragma unroll
    for (int c = 0; c < BN / (8 * TW); ++c) {
      const int r0 = wave * (BN / TW) + c * 8;
      GLD_LDS(BT + (size_t)(col0 + r0 + l8) * K + kt + srcCol, Blds + r0 * 64);
    }
    __syncthreads();
    #pragma unroll
    for (int kk = 0; kk < 2; ++kk) {
      bf16x8 af[MF], bf[NF];
      #pragma unroll
      for (int m = 0; m < MF; ++m) {
        const int row = wm + m * 16 + r15;
        af[m] = *(const bf16x8*)((const char*)Alds + row * 128 + ((kk*64 + g*16) ^ ((row & 7) << 4)));
      }
      #pragma unroll
      for (int n = 0; n < NF; ++n) {
        const int row = wn + n * 16 + r15;
        bf[n] = *(const bf16x8*)((const char*)Blds + row * 128 + ((kk*64 + g*16) ^ ((row & 7) << 4)));
      }
      #pragma unroll
      for (int m = 0; m < MF; ++m)
        #pragma unroll
        for (int n = 0; n < NF; ++n)
          acc[m][n] = __builtin_amdgcn_mfma_f32_16x16x32_bf16(af[m], bf[n], acc[m][n], 0, 0, 0);
    }
    __syncthreads();
  }

  if constexpr (FINAL) {
    #pragma unroll
    for (int m = 0; m < MF; ++m)
      #pragma unroll
      for (int n = 0; n < NF; ++n) {
        const int row = row0 + wm + m * 16 + g * 4;
        const int col = col0 + wn + n * 16 + r15;
        const float bv = bias[col];
        #pragma unroll
        for (int r = 0; r < 4; ++r)
          outF[(size_t)(row + r) * N + col] = acc[m][n][r] + bv;
      }
  } else {
    if (col0 < 2048) {
      // Q/K tile: row-major store into qkvQK [4096][2048]
      #pragma unroll
      for (int m = 0; m < MF; ++m)
        #pragma unroll
        for (int n = 0; n < NF; ++n) {
          const int row = row0 + wm + m * 16 + g * 4;
          const int col = col0 + wn + n * 16 + r15;
          #pragma unroll
          for (int r = 0; r < 4; ++r)
            outB[(size_t)(row + r) * 2048 + col] = f2bf(acc[m][n][r]);
        }
    } else {
      // V tile: transposed sigma-permuted store into vt [32 bh][64 d][2048 n']
      #pragma unroll
      for (int m = 0; m < MF; ++m)
        #pragma unroll
        for (int n = 0; n < NF; ++n) {
          const int row = row0 + wm + m * 16 + g * 4;    // = bb*2048 + nseq
          const int bb = row >> 11, ns = row & 2047;     // bits 0-1 of ns are 0
          const int hh = (col0 + wn - 2048) >> 6;        // wave-uniform head
          const int dd = (wn + n * 16 + r15) & 63;       // d within head
          uint2 o;
          o.x = cvt_pk_bf16(acc[m][n][0], acc[m][n][1]); // n'+0, n'+1
          o.y = cvt_pk_bf16(acc[m][n][2], acc[m][n][3]); // n'+2, n'+3
          *(uint2*)&outV[((size_t)((bb * 16 + hh) * 64 + dd)) * 2048 + vpos(ns)] = o;
        }
    }
  }
}

// ---------------- Flash attention v11: global V with register double-buffer ----------------
// v10 proved the global-V data path correct (absmax 2e-3) but its same-iteration
// vmcnt(2)+sched_barrier wait exposed L2 latency serially (136us, MfmaUtil 11%).
// v11 moves the consume one iteration back: vf[nxt] (tile kt+1) is PREFETCHED at the top
// of iter kt; PV(kt) uses vf[cur] loaded during iter kt-1 and already drained by the
// intervening __syncthreads() vmcnt(0) barrier drain -> no manual waits at all.
// Static buffer indexing via #pragma unroll 2 (cur/nxt constant-folded). LDS = K only (16KB).
__global__ __launch_bounds__(256, 4) void attn_kernel(const u16* __restrict__ qkvQK,
                                                      const u16* __restrict__ vt,
                                                      u16* __restrict__ attnO)
{
  __shared__ __align__(16) u16 Klds[2][64 * 64];   // [key][d], XOR-swizzled rows

  const int tid = threadIdx.x, wave = tid >> 6, lane = tid & 63;
  const int r15 = lane & 15, g = lane >> 4, l8 = lane >> 3, c8 = lane & 7;

  // XCD-clustered remap (bijective; XCD k = lin%8 gets bh in {4k..4k+3})
  const int lin = blockIdx.x + (blockIdx.y << 5);
  const int bh = ((lin & 7) << 2) | ((lin >> 3) & 3);
  const int qt = lin >> 5;
  const int b = bh >> 4, h = bh & 15;

  const u16* Qp = qkvQK + (size_t)b * 2048 * 2048 + h * 64;
  const u16* Kp = Qp + 1024;
  const u16* Vt = vt + (size_t)bh * 64 * 2048;

  const int q0 = qt * 64 + wave * 16;

  // Q fragments (B operand of QK): lane r15 = q-row
  bf16x8 qf[2];
  #pragma unroll
  for (int kk = 0; kk < 2; ++kk)
    qf[kk] = *(const bf16x8*)(Qp + (size_t)(q0 + r15) * 2048 + kk*32 + g*8);

  f32x4 acc[4] = {};   // acc[nf]: q = r15, d = nf*16 + g*4 + r
  f32x4 accl = {};     // l for q-row r15 (all 4 regs identical; ones-A MFMA)

  const int srcCol = (c8 ^ l8) << 3;

  // ones A-fragment for the l-sum MFMA
  const unsigned int one2 = 0x3F803F80u;
  uint4 onesu; onesu.x = one2; onesu.y = one2; onesu.z = one2; onesu.w = one2;
  const bf16x8 onesf = *(const bf16x8*)&onesu;

  // invariant LDS fragment byte offsets; (row&7)==(r15&7) since row=m*16+r15
  int offp[2][4];
  #pragma unroll
  for (int kk = 0; kk < 2; ++kk)
    #pragma unroll
    for (int m = 0; m < 4; ++m)
      offp[kk][m] = (m * 16 + r15) * 128 + ((kk * 64 + g * 16) ^ ((r15 & 7) << 4));

  // V^T global row bases (A operand of PV): row d = nf*16 + r15
  const u16* vrow[4];
  #pragma unroll
  for (int nf = 0; nf < 4; ++nf)
    vrow[nf] = Vt + (size_t)(nf * 16 + r15) * 2048 + g * 8;

  // prologue: stage K tile 0 + load V fragments for tile 0 into buffer 0
  bf16x8 vf[2][2][4];  // [buf][kk][nf]
  #pragma unroll
  for (int c = 0; c < 2; ++c) {
    const int r0 = wave * 16 + c * 8;
    GLD_LDS(Kp + (size_t)(r0 + l8) * 2048 + srcCol, &Klds[0][r0 * 64]);
  }
  #pragma unroll
  for (int kk = 0; kk < 2; ++kk)
    #pragma unroll
    for (int nf = 0; nf < 4; ++nf)
      vf[0][kk][nf] = *(const bf16x8*)(vrow[nf] + kk*32);
  __syncthreads();

  #pragma unroll 2
  for (int kt = 0; kt < 32; ++kt) {
    const int cur = kt & 1, nxt = cur ^ 1;
    const int kn = (kt < 31) ? kt + 1 : 31;

    // 1) prefetch NEXT tile's V fragments into vf[nxt] (consumed next iteration;
    //    drained by this iteration's end-of-loop barrier)
    #pragma unroll
    for (int kk = 0; kk < 2; ++kk)
      #pragma unroll
      for (int nf = 0; nf < 4; ++nf)
        vf[nxt][kk][nf] = *(const bf16x8*)(vrow[nf] + kn*64 + kk*32);

    // 2) stage next K tile (unconditional: last iter re-stages 31 into dead buffer)
    #pragma unroll
    for (int c = 0; c < 2; ++c) {
      const int r0 = wave * 16 + c * 8;
      GLD_LDS(Kp + (size_t)(kn*64 + r0 + l8) * 2048 + srcCol, &Klds[nxt][r0 * 64]);
    }

    // 3) S^T = K x Q: s[m][r] = score(q=r15, key = m*16 + g*4 + r), log2 domain
    const char* kbase = (const char*)&Klds[cur][0];
    bf16x8 kf[2][4];
    #pragma unroll
    for (int kk = 0; kk < 2; ++kk)
      #pragma unroll
      for (int m = 0; m < 4; ++m)
        kf[kk][m] = *(const bf16x8*)(kbase + offp[kk][m]);
    f32x4 s[4] = {};
    __builtin_amdgcn_s_setprio(1);
    #pragma unroll
    for (int kk = 0; kk < 2; ++kk)
      #pragma unroll
      for (int m = 0; m < 4; ++m)
        s[m] = __builtin_amdgcn_mfma_f32_16x16x32_bf16(kf[kk][m], qf[kk], s[m], 0, 0, 0);
    __builtin_amdgcn_s_setprio(0);

    // 4) P = exp2(S), unnormalized (no max: log2-domain scores, |S| <~ 10); pack
    #pragma unroll
    for (int m = 0; m < 4; ++m)
      #pragma unroll
      for (int r = 0; r < 4; ++r)
        s[m][r] = __builtin_amdgcn_exp2f(s[m][r]);
    unsigned int u[4][2];
    #pragma unroll
    for (int m = 0; m < 4; ++m) {
      u[m][0] = cvt_pk_bf16(s[m][0], s[m][1]);
      u[m][1] = cvt_pk_bf16(s[m][2], s[m][3]);
    }
    uint4 pw[2];
    pw[0].x = u[0][0]; pw[0].y = u[0][1]; pw[0].z = u[1][0]; pw[0].w = u[1][1];
    pw[1].x = u[2][0]; pw[1].y = u[2][1]; pw[1].z = u[3][0]; pw[1].w = u[3][1];

    // 5) O^T += V^T x P^T ; l += ones x P^T — vf[cur] loaded last iteration,
    //    already complete (previous barrier drained vmcnt); compiler tracks the reg dep.
    __builtin_amdgcn_s_setprio(1);
    #pragma unroll
    for (int kk = 0; kk < 2; ++kk) {
      const bf16x8 pfk = *(const bf16x8*)&pw[kk];
      accl = __builtin_amdgcn_mfma_f32_16x16x32_bf16(onesf, pfk, accl, 0, 0, 0);
      #pragma unroll
      for (int nf = 0; nf < 4; ++nf)
        acc[nf] = __builtin_amdgcn_mfma_f32_16x16x32_bf16(vf[cur][kk][nf], pfk, acc[nf], 0, 0, 0);
    }
    __builtin_amdgcn_s_setprio(0);

    __syncthreads();
  }

  // epilogue: normalize by lane-local l (accl regs all equal) and store 8B per nf
  const float linv = 1.0f / accl[0];
  const size_t base = (size_t)(b * 2048 + q0 + r15) * 1024 + h * 64;
  #pragma unroll
  for (int nf = 0; nf < 4; ++nf) {
    uint2 o;
    o.x = cvt_pk_bf16(acc[nf][0] * linv, acc[nf][1] * linv);
    o.y = cvt_pk_bf16(acc[nf][2] * linv, acc[nf][3] * linv);
    *(uint2*)&attnO[base + nf*16 + g*4] = o;
  }
}

// ---------------------------------------------------------------------------
extern "C" void kernel_launch(void* const* d_in, const int* in_sizes, int n_in,
                              void* d_out, int out_size, void* d_ws, size_t ws_size,
                              hipStream_t stream) {
  const float* x     = (const float*)d_in[0];
  const float* gamma = (const float*)d_in[1];
  const float* beta  = (const float*)d_in[2];
  const float* w_qkv = (const float*)d_in[3];
  const float* w_out = (const float*)d_in[4];
  const float* b_out = (const float*)d_in[5];
  float* out = (float*)d_out;
  char* ws = (char*)d_ws;

  u16* xn    = (u16*)(ws);                     //  8 MB: [4096][1024]
  u16* wqkvT = (u16*)(ws + ( 8u << 20));       //  6 MB: [3072][1024] (q rows pre-scaled 0.125*log2e)
  u16* qkvQK = (u16*)(ws + (14u << 20));       // 16 MB: [4096][2048] (Q,K only)
  u16* vtbuf = (u16*)(ws + (30u << 20));       //  8 MB: [32 bh][64 d][2048 n'] (sigma-permuted)
  u16* woutT = (u16*)(ws + (38u << 20));       //  2 MB: [1024][1024]
  u16* attnO = (u16*)(ws + (40u << 20));       //  8 MB: [4096][1024]

  prep_kernel<<<8192, 256, 0, stream>>>(x, gamma, beta, xn, w_qkv, wqkvT, w_out, woutT);
  gemm_bt<false, 128, 2, 2><<<dim3(24, 32), 256, 0, stream>>>(xn, wqkvT, qkvQK, vtbuf, nullptr, nullptr, 4096, 3072, 1024);
  attn_kernel<<<dim3(32, 32), 256, 0, stream>>>(qkvQK, vtbuf, attnO);
  gemm_bt<true, 64, 2, 2><<<dim3(16, 32), 256, 0, stream>>>(attnO, woutT, nullptr, nullptr, out, b_out, 4096, 1024, 1024);
}

// Round 18
// 101.748 us; speedup vs baseline: 2.3247x; 2.3247x over previous
//
#include <hip/hip_runtime.h>

typedef unsigned short u16;
typedef __attribute__((ext_vector_type(8))) __bf16 bf16x8;
typedef __attribute__((ext_vector_type(4))) float f32x4;

#define GLD_LDS(src, dst) \
  __builtin_amdgcn_global_load_lds((const __attribute__((address_space(1))) void*)(src), \
                                   (__attribute__((address_space(3))) void*)(dst), 16, 0, 0)

__device__ __forceinline__ u16 f2bf(float f) {
  union { float f; unsigned int u; } c; c.f = f;
  unsigned int u = c.u + 0x7FFFu + ((c.u >> 16) & 1u);
  return (u16)(u >> 16);
}

__device__ __forceinline__ unsigned int cvt_pk_bf16(float lo, float hi) {
  unsigned int r;
  asm("v_cvt_pk_bf16_f32 %0, %1, %2" : "=v"(r) : "v"(lo), "v"(hi));
  return r;
}

// sigma key-permutation within each 64-block (bit perm: keeps bits 0,1,5; 2->3->4->2)
// so attn's P^T B-fragment is exactly the lane-local cvt_pk-packed S registers.
__device__ __forceinline__ int vpos(int n) {
  return (n & ~63) | (n & 0x23) | ((n & 0x0C) << 1) | ((n & 0x10) >> 2);
}

// ---------------- Fused prep: LN + both weight transposes in ONE dispatch ----------------
__device__ __forceinline__ void ln_body(const float* __restrict__ x,
    const float* __restrict__ gamma, const float* __restrict__ beta,
    u16* __restrict__ xn, int row, int tid, float* red)
{
  const int lane = tid & 63, wave = tid >> 6;
  const float4 v = ((const float4*)(x + (size_t)row * 1024))[tid];
  float s = v.x + v.y + v.z + v.w;
  float q = v.x*v.x + v.y*v.y + v.z*v.z + v.w*v.w;
  #pragma unroll
  for (int m = 1; m < 64; m <<= 1) { s += __shfl_xor(s, m, 64); q += __shfl_xor(q, m, 64); }
  if (lane == 0) { red[wave] = s; red[4 + wave] = q; }
  __syncthreads();
  s = red[0] + red[1] + red[2] + red[3];
  q = red[4] + red[5] + red[6] + red[7];
  const float mu = s * (1.0f/1024.0f);
  const float var = q * (1.0f/1024.0f) - mu*mu;
  const float rs = rsqrtf(var + 1e-5f);
  const float4 gm = ((const float4*)gamma)[tid];
  const float4 bt = ((const float4*)beta)[tid];
  unsigned int w0 = (unsigned int)f2bf((v.x - mu)*rs*gm.x + bt.x)
                  | ((unsigned int)f2bf((v.y - mu)*rs*gm.y + bt.y) << 16);
  unsigned int w1 = (unsigned int)f2bf((v.z - mu)*rs*gm.z + bt.z)
                  | ((unsigned int)f2bf((v.w - mu)*rs*gm.w + bt.w) << 16);
  uint2 o; o.x = w0; o.y = w1;
  ((uint2*)(xn + (size_t)row * 1024))[tid] = o;
}

__device__ __forceinline__ void tcvt_body(const float* __restrict__ in, u16* __restrict__ out,
    int K, int N, int scaleLim, int bx, int by, int tid, float* t /*32x33*/)
{
  const int n0 = bx * 32, k0 = by * 32;
  const int lx = tid & 31, ly = tid >> 5;  // 32x8
  #pragma unroll
  for (int i = 0; i < 32; i += 8)
    t[(ly + i) * 33 + lx] = in[(size_t)(k0 + ly + i) * N + n0 + lx];
  __syncthreads();
  #pragma unroll
  for (int i = 0; i < 32; i += 8) {
    int n = n0 + ly + i;
    float v = t[lx * 33 + ly + i];
    if (n < scaleLim) v *= 0.18033688011116011f;   // 0.125 * log2(e)
    out[(size_t)n * K + k0 + lx] = f2bf(v);
  }
}

__global__ __launch_bounds__(256) void prep_kernel(
    const float* __restrict__ x, const float* __restrict__ gamma,
    const float* __restrict__ beta, u16* __restrict__ xn,
    const float* __restrict__ w_qkv, u16* __restrict__ wqkvT,
    const float* __restrict__ w_out, u16* __restrict__ woutT)
{
  __shared__ float smem[32 * 33];
  const int blk = blockIdx.x, tid = threadIdx.x;
  if (blk < 4096) {
    ln_body(x, gamma, beta, xn, blk, tid, smem);
  } else if (blk < 4096 + 3072) {
    const int j = blk - 4096;
    tcvt_body(w_qkv, wqkvT, 1024, 3072, 1024, j % 96, j / 96, tid, smem);
  } else {
    const int j = blk - 7168;
    tcvt_body(w_out, woutT, 1024, 1024, 0, j % 32, j / 32, tid, smem);
  }
}

// ---------------- GEMM: C[M][N] = A[M][K] * BT[N][K]^T, bf16 in, fp32 acc ----------------
// Single-buffer + XCD swizzle (r10/r13-verified), templated on BN and wave grid WMxWN.
// !FINAL (gemm1, N=3072): cols <2048 (Q,K) -> outB [4096][2048]; cols >=2048 (V) -> written
// TRANSPOSED + sigma-permuted directly into outV (vt) from the accumulator (r14-verified).
template<bool FINAL, int BN, int WM, int WN>
__global__ __launch_bounds__(WM*WN*64, 2) void gemm_bt(
    const u16* __restrict__ A, const u16* __restrict__ BT,
    u16* __restrict__ outB, u16* __restrict__ outV, float* __restrict__ outF,
    const float* __restrict__ bias, int M, int N, int K)
{
  constexpr int TW = WM * WN;          // waves per block
  constexpr int MF = 128 / (16 * WM);  // m-frags per wave
  constexpr int NF = BN / (16 * WN);   // n-frags per wave
  __shared__ __align__(16) u16 Alds[128 * 64];
  __shared__ __align__(16) u16 Blds[BN * 64];
  const int tid = threadIdx.x, wave = tid >> 6, lane = tid & 63;
  const int r15 = lane & 15, g = lane >> 4, l8 = lane >> 3, c8 = lane & 7;

  // XCD swizzle (bijective: nwg % 8 == 0)
  const int nwgx = gridDim.x;
  const int lin = blockIdx.x + blockIdx.y * nwgx;
  const int cpx = (nwgx * gridDim.y) >> 3;
  const int swz = (lin & 7) * cpx + (lin >> 3);
  const int row0 = (swz / nwgx) * 128, col0 = (swz % nwgx) * BN;

  const int wm = (wave / WN) * (128 / WM);
  const int wn = (wave % WN) * (BN / WN);
  const int srcCol = (c8 ^ l8) << 3;

  f32x4 acc[MF][NF] = {};

  for (int kt = 0; kt < K; kt += 64) {
    #pragma unroll
    for (int c = 0; c < 16 / TW; ++c) {
      const int r0 = wave * (128 / TW) + c * 8;
      GLD_LDS(A + (size_t)(row0 + r0 + l8) * K + kt + srcCol, Alds + r0 * 64);
    }
    #pragma unroll
    for (int c = 0; c < BN / (8 * TW); ++c) {
      const int r0 = wave * (BN / TW) + c * 8;
      GLD_LDS(BT + (size_t)(col0 + r0 + l8) * K + kt + srcCol, Blds + r0 * 64);
    }
    __syncthreads();
    #pragma unroll
    for (int kk = 0; kk < 2; ++kk) {
      bf16x8 af[MF], bf[NF];
      #pragma unroll
      for (int m = 0; m < MF; ++m) {
        const int row = wm + m * 16 + r15;
        af[m] = *(const bf16x8*)((const char*)Alds + row * 128 + ((kk*64 + g*16) ^ ((row & 7) << 4)));
      }
      #pragma unroll
      for (int n = 0; n < NF; ++n) {
        const int row = wn + n * 16 + r15;
        bf[n] = *(const bf16x8*)((const char*)Blds + row * 128 + ((kk*64 + g*16) ^ ((row & 7) << 4)));
      }
      #pragma unroll
      for (int m = 0; m < MF; ++m)
        #pragma unroll
        for (int n = 0; n < NF; ++n)
          acc[m][n] = __builtin_amdgcn_mfma_f32_16x16x32_bf16(af[m], bf[n], acc[m][n], 0, 0, 0);
    }
    __syncthreads();
  }

  if constexpr (FINAL) {
    #pragma unroll
    for (int m = 0; m < MF; ++m)
      #pragma unroll
      for (int n = 0; n < NF; ++n) {
        const int row = row0 + wm + m * 16 + g * 4;
        const int col = col0 + wn + n * 16 + r15;
        const float bv = bias[col];
        #pragma unroll
        for (int r = 0; r < 4; ++r)
          outF[(size_t)(row + r) * N + col] = acc[m][n][r] + bv;
      }
  } else {
    if (col0 < 2048) {
      // Q/K tile: row-major store into qkvQK [4096][2048]
      #pragma unroll
      for (int m = 0; m < MF; ++m)
        #pragma unroll
        for (int n = 0; n < NF; ++n) {
          const int row = row0 + wm + m * 16 + g * 4;
          const int col = col0 + wn + n * 16 + r15;
          #pragma unroll
          for (int r = 0; r < 4; ++r)
            outB[(size_t)(row + r) * 2048 + col] = f2bf(acc[m][n][r]);
        }
    } else {
      // V tile: transposed sigma-permuted store into vt [32 bh][64 d][2048 n']
      #pragma unroll
      for (int m = 0; m < MF; ++m)
        #pragma unroll
        for (int n = 0; n < NF; ++n) {
          const int row = row0 + wm + m * 16 + g * 4;    // = bb*2048 + nseq
          const int bb = row >> 11, ns = row & 2047;     // bits 0-1 of ns are 0
          const int hh = (col0 + wn - 2048) >> 6;        // wave-uniform head
          const int dd = (wn + n * 16 + r15) & 63;       // d within head
          uint2 o;
          o.x = cvt_pk_bf16(acc[m][n][0], acc[m][n][1]); // n'+0, n'+1
          o.y = cvt_pk_bf16(acc[m][n][2], acc[m][n][3]); // n'+2, n'+3
          *(uint2*)&outV[((size_t)((bb * 16 + hh) * 64 + dd)) * 2048 + vpos(ns)] = o;
        }
    }
  }
}

// ---------------- Flash attention v6 + T5 setprio (verified r15: 46.9us) ----------------
// no-max exp2 softmax (log2-domain scores, |S|<~10), sigma-permuted V -> zero-relayout P,
// dbuf K/V, 1 barrier/iter, l-sum on the matrix pipe via ones-A MFMA.
__global__ __launch_bounds__(256, 4) void attn_kernel(const u16* __restrict__ qkvQK,
                                                      const u16* __restrict__ vt,
                                                      u16* __restrict__ attnO)
{
  __shared__ __align__(16) u16 Klds[2][64 * 64];   // [key][d], XOR-swizzled rows
  __shared__ __align__(16) u16 Vlds[2][64 * 64];   // [d][key'], XOR-swizzled rows

  const int tid = threadIdx.x, wave = tid >> 6, lane = tid & 63;
  const int r15 = lane & 15, g = lane >> 4, l8 = lane >> 3, c8 = lane & 7;
  const int bh = blockIdx.x, qt = blockIdx.y;
  const int b = bh >> 4, h = bh & 15;

  const u16* Qp = qkvQK + (size_t)b * 2048 * 2048 + h * 64;
  const u16* Kp = Qp + 1024;
  const u16* Vt = vt + (size_t)bh * 64 * 2048;

  const int q0 = qt * 64 + wave * 16;

  // Q fragments (B operand of QK): lane r15 = q-row
  bf16x8 qf[2];
  #pragma unroll
  for (int kk = 0; kk < 2; ++kk)
    qf[kk] = *(const bf16x8*)(Qp + (size_t)(q0 + r15) * 2048 + kk*32 + g*8);

  f32x4 acc[4] = {};   // acc[nf]: q = r15, d = nf*16 + g*4 + r
  f32x4 accl = {};     // l for q-row r15 (all 4 regs identical; ones-A MFMA)

  const int srcCol = (c8 ^ l8) << 3;

  // ones A-fragment for the l-sum MFMA
  const unsigned int one2 = 0x3F803F80u;
  uint4 onesu; onesu.x = one2; onesu.y = one2; onesu.z = one2; onesu.w = one2;
  const bf16x8 onesf = *(const bf16x8*)&onesu;

  // invariant LDS fragment byte offsets (8 VGPRs); (row&7)==(r15&7) since row=m*16+r15
  int offp[2][4];
  #pragma unroll
  for (int kk = 0; kk < 2; ++kk)
    #pragma unroll
    for (int m = 0; m < 4; ++m)
      offp[kk][m] = (m * 16 + r15) * 128 + ((kk * 64 + g * 16) ^ ((r15 & 7) << 4));

  // prologue: stage tile 0
  #pragma unroll
  for (int c = 0; c < 2; ++c) {
    const int r0 = wave * 16 + c * 8;
    GLD_LDS(Kp + (size_t)(r0 + l8) * 2048 + srcCol, &Klds[0][r0 * 64]);
    GLD_LDS(Vt + (size_t)(r0 + l8) * 2048 + srcCol, &Vlds[0][r0 * 64]);
  }
  __syncthreads();

  #pragma unroll 2
  for (int kt = 0; kt < 32; ++kt) {
    const int cur = kt & 1;
    if (kt < 31) {
      const int nxt = cur ^ 1, kn = kt + 1;
      #pragma unroll
      for (int c = 0; c < 2; ++c) {
        const int r0 = wave * 16 + c * 8;
        GLD_LDS(Kp + (size_t)(kn*64 + r0 + l8) * 2048 + srcCol, &Klds[nxt][r0 * 64]);
        GLD_LDS(Vt + (size_t)(r0 + l8) * 2048 + kn*64 + srcCol, &Vlds[nxt][r0 * 64]);
      }
    }

    // S^T = K x Q: s[m][r] = score(q=r15, key = m*16 + g*4 + r), log2 domain
    const char* kbase = (const char*)&Klds[cur][0];
    bf16x8 kf[2][4];
    #pragma unroll
    for (int kk = 0; kk < 2; ++kk)
      #pragma unroll
      for (int m = 0; m < 4; ++m)
        kf[kk][m] = *(const bf16x8*)(kbase + offp[kk][m]);
    f32x4 s[4] = {};
    __builtin_amdgcn_s_setprio(1);
    #pragma unroll
    for (int kk = 0; kk < 2; ++kk)
      #pragma unroll
      for (int m = 0; m < 4; ++m)
        s[m] = __builtin_amdgcn_mfma_f32_16x16x32_bf16(kf[kk][m], qf[kk], s[m], 0, 0, 0);
    __builtin_amdgcn_s_setprio(0);

    // P = exp2(S), unnormalized (no max, no rescale — see header comment)
    #pragma unroll
    for (int m = 0; m < 4; ++m)
      #pragma unroll
      for (int r = 0; r < 4; ++r)
        s[m][r] = __builtin_amdgcn_exp2f(s[m][r]);

    // pack P: B-frag of P^T = lane-local packed words in order (sigma-permuted V)
    unsigned int u[4][2];
    #pragma unroll
    for (int m = 0; m < 4; ++m) {
      u[m][0] = cvt_pk_bf16(s[m][0], s[m][1]);
      u[m][1] = cvt_pk_bf16(s[m][2], s[m][3]);
    }
    uint4 pw[2];
    pw[0].x = u[0][0]; pw[0].y = u[0][1]; pw[0].z = u[1][0]; pw[0].w = u[1][1];
    pw[1].x = u[2][0]; pw[1].y = u[2][1]; pw[1].z = u[3][0]; pw[1].w = u[3][1];

    // O^T += V^T x P^T ; l += ones x P^T (matrix pipe)
    const char* vbase = (const char*)&Vlds[cur][0];
    bf16x8 vf[2][4];
    #pragma unroll
    for (int kk = 0; kk < 2; ++kk)
      #pragma unroll
      for (int nf = 0; nf < 4; ++nf)
        vf[kk][nf] = *(const bf16x8*)(vbase + offp[kk][nf]);
    __builtin_amdgcn_s_setprio(1);
    #pragma unroll
    for (int kk = 0; kk < 2; ++kk) {
      const bf16x8 pfk = *(const bf16x8*)&pw[kk];
      accl = __builtin_amdgcn_mfma_f32_16x16x32_bf16(onesf, pfk, accl, 0, 0, 0);
      #pragma unroll
      for (int nf = 0; nf < 4; ++nf)
        acc[nf] = __builtin_amdgcn_mfma_f32_16x16x32_bf16(vf[kk][nf], pfk, acc[nf], 0, 0, 0);
    }
    __builtin_amdgcn_s_setprio(0);

    __syncthreads();
  }

  // epilogue: normalize by lane-local l (accl regs all equal) and store 8B per nf
  const float linv = 1.0f / accl[0];
  const size_t base = (size_t)(b * 2048 + q0 + r15) * 1024 + h * 64;
  #pragma unroll
  for (int nf = 0; nf < 4; ++nf) {
    uint2 o;
    o.x = cvt_pk_bf16(acc[nf][0] * linv, acc[nf][1] * linv);
    o.y = cvt_pk_bf16(acc[nf][2] * linv, acc[nf][3] * linv);
    *(uint2*)&attnO[base + nf*16 + g*4] = o;
  }
}

// ---------------------------------------------------------------------------
extern "C" void kernel_launch(void* const* d_in, const int* in_sizes, int n_in,
                              void* d_out, int out_size, void* d_ws, size_t ws_size,
                              hipStream_t stream) {
  const float* x     = (const float*)d_in[0];
  const float* gamma = (const float*)d_in[1];
  const float* beta  = (const float*)d_in[2];
  const float* w_qkv = (const float*)d_in[3];
  const float* w_out = (const float*)d_in[4];
  const float* b_out = (const float*)d_in[5];
  float* out = (float*)d_out;
  char* ws = (char*)d_ws;

  u16* xn    = (u16*)(ws);                     //  8 MB: [4096][1024]
  u16* wqkvT = (u16*)(ws + ( 8u << 20));       //  6 MB: [3072][1024] (q rows pre-scaled 0.125*log2e)
  u16* qkvQK = (u16*)(ws + (14u << 20));       // 16 MB: [4096][2048] (Q,K only)
  u16* vtbuf = (u16*)(ws + (30u << 20));       //  8 MB: [32 bh][64 d][2048 n'] (sigma-permuted)
  u16* woutT = (u16*)(ws + (38u << 20));       //  2 MB: [1024][1024]
  u16* attnO = (u16*)(ws + (40u << 20));       //  8 MB: [4096][1024]

  prep_kernel<<<8192, 256, 0, stream>>>(x, gamma, beta, xn, w_qkv, wqkvT, w_out, woutT);
  gemm_bt<false, 128, 2, 2><<<dim3(24, 32), 256, 0, stream>>>(xn, wqkvT, qkvQK, vtbuf, nullptr, nullptr, 4096, 3072, 1024);
  attn_kernel<<<dim3(32, 32), 256, 0, stream>>>(qkvQK, vtbuf, attnO);
  gemm_bt<true, 64, 2, 2><<<dim3(16, 32), 256, 0, stream>>>(attnO, woutT, nullptr, nullptr, out, b_out, 4096, 1024, 1024);
}